// Round 3
// baseline (304.466 us; speedup 1.0000x reference)
//
#include <hip/hip_runtime.h>

#define NB 512
#define NC 512
#define HD 128

typedef float4 f4;

// ---- uniform 32 KB tile staging: 8192 floats, 512 threads x 4 float4 ----
#define TILE_PUT() { _Pragma("unroll") for (int i_=0;i_<4;++i_) ((f4*)Wb)[i_*512+tid]=pf[i_]; }
#define TILE_GET(p) { const f4* s_=(const f4*)(p); _Pragma("unroll") for (int i_=0;i_<4;++i_) pf[i_]=s_[i_*512+tid]; }

// one pipeline round: barrier; commit prefetched tile to LDS; issue next tile's
// loads (cover latency under this round's compute); barrier; compute body.
#define ROUND(nextsrc, ...) { \
  __syncthreads(); \
  TILE_PUT(); \
  { const float* n_ = (nextsrc); if (n_) TILE_GET(n_); } \
  __syncthreads(); \
  __VA_ARGS__; }

// 64-k matmul chunk: acc0/1 += A[arow][koff+k] * Wtile[k][c2 / c2+1]
// A-read is wave-uniform broadcast; W-read is 512B contiguous per wave.
#define MM64(Aptr, astride, arow, koff) { \
  _Pragma("unroll") for (int k_=0;k_<64;++k_) { \
    float a_ = (Aptr)[(arow)*(astride) + (koff) + k_]; \
    float2 w_ = *(const float2*)&Wb[k_*HD + c2]; \
    acc0 = fmaf(a_, w_.x, acc0); acc1 = fmaf(a_, w_.y, acc1); } }

// ---------------------------------------------------------------------------
// k_pre: blocks 0-63 bird-init (x0 + u), 64-127 color-init (x0 + v),
//        128-639 per-row stable-descending argsort (lax.top_k semantics).
// ---------------------------------------------------------------------------
__global__ __launch_bounds__(512) void k_pre(
    const float* __restrict__ probs, const float* __restrict__ npw,
    const float* __restrict__ npb, const float* __restrict__ ew1,
    const float* __restrict__ eb1, float* __restrict__ x0,
    float* __restrict__ u, float* __restrict__ v, int* __restrict__ idx) {
  __shared__ float smem[13312];   // 52 KB
  const int tid = threadIdx.x;
  const int b = blockIdx.x;

  if (b >= 128) {                 // ---------- sort ----------
    float* s = smem;
    const int row = b - 128;
    s[tid] = probs[row * NC + tid];
    __syncthreads();
    const float myv = s[tid];
    int rank = 0;
    for (int j4 = 0; j4 < 128; ++j4) {
      f4 sv = ((const f4*)s)[j4];
      int j = j4 * 4;
      rank += (sv.x > myv) || (sv.x == myv && (j + 0) < tid);
      rank += (sv.y > myv) || (sv.y == myv && (j + 1) < tid);
      rank += (sv.z > myv) || (sv.z == myv && (j + 2) < tid);
      rank += (sv.w > myv) || (sv.w == myv && (j + 3) < tid);
    }
    idx[row * NC + rank] = tid;
    return;
  }

  float* Wb = smem;                                        // 8192 floats
  const int c2 = (tid & 63) * 2;
  const int row = tid >> 6;
  f4 pf[4];

  if (b < 64) {                   // ---------- bird rows ----------
    float (*Ps)[NC] = (float(*)[NC])(smem + 8192);         // 8x512
    float (*xs)[HD] = (float(*)[HD])(smem + 8192 + 4096);  // 8x128
    const int r0 = b * 8;
    { const f4* p4 = (const f4*)(probs + r0 * NC);
      ((f4*)Ps)[tid] = p4[tid]; ((f4*)Ps)[512 + tid] = p4[512 + tid]; }
    TILE_GET(npw);
    float2 bb = *(const float2*)&npb[c2];
    float2 be = *(const float2*)&eb1[c2];
    float acc0 = bb.x, acc1 = bb.y;
    for (int t = 0; t < 8; ++t) {                          // probs @ npw
      const float* ns = (t < 7) ? (npw + (t + 1) * 8192) : ew1;
      ROUND(ns, MM64(&Ps[0][0], NC, row, t * 64));
    }
    xs[row][c2] = acc0; xs[row][c2 + 1] = acc1;
    *(float2*)&x0[(r0 + row) * HD + c2] = make_float2(acc0, acc1);
    acc0 = be.x; acc1 = be.y;                              // u = xs @ ew1_top
    ROUND(ew1 + 8192, MM64(&xs[0][0], HD, row, 0));
    ROUND(nullptr,    MM64(&xs[0][0], HD, row, 64));
    *(float2*)&u[(r0 + row) * HD + c2] = make_float2(acc0, acc1);
  } else {                        // ---------- color rows ----------
    float (*xs)[HD] = (float(*)[HD])(smem + 8192 + 4096);
    const int c0 = (b - 64) * 8;
    float2 wv = *(const float2*)&npw[(c0 + row) * HD + c2];
    float2 bb = *(const float2*)&npb[c2];
    float xv0 = wv.x + bb.x, xv1 = wv.y + bb.y;
    xs[row][c2] = xv0; xs[row][c2 + 1] = xv1;
    *(float2*)&x0[(NB + c0 + row) * HD + c2] = make_float2(xv0, xv1);
    TILE_GET(ew1 + 16384);                                 // ew1 bottom half
    float acc0 = 0.f, acc1 = 0.f;
    ROUND(ew1 + 16384 + 8192, MM64(&xs[0][0], HD, row, 0));
    ROUND(nullptr,            MM64(&xs[0][0], HD, row, 64));
    *(float2*)&v[(c0 + row) * HD + c2] = make_float2(acc0, acc1);
  }
}

// ---------------------------------------------------------------------------
// k_RS: blocks 0-63 -> R (8 bird rows each), 64-127 -> S (8 color rows each).
// other[] streamed through LDS in 32 KB tiles with reg-prefetch.
// ---------------------------------------------------------------------------
__global__ __launch_bounds__(512) void k_RS(const float* __restrict__ u,
                                            const float* __restrict__ v,
                                            float* __restrict__ RS) {
  __shared__ float smem[8192];
  float* Wb = smem;
  const int tid = threadIdx.x;
  const int b = blockIdx.x;
  const int h2 = (tid & 63) * 2;
  const int row = tid >> 6;
  const float *mine, *other; int r0, ob;
  if (b < 64) { mine = u; other = v; r0 = b * 8;        ob = r0; }
  else        { mine = v; other = u; r0 = (b - 64) * 8; ob = NB + r0; }
  float2 base = *(const float2*)&mine[(r0 + row) * HD + h2];
  f4 pf[4];
  TILE_GET(other);
  float acc0 = 0.f, acc1 = 0.f;
  for (int t = 0; t < 8; ++t) {
    const float* ns = (t < 7) ? (other + (t + 1) * 8192) : (const float*)nullptr;
    ROUND(ns, {
      _Pragma("unroll 16") for (int j = 0; j < 64; ++j) {
        float2 o = *(const float2*)&Wb[j * HD + h2];
        acc0 += fmaxf(base.x + o.x, 0.f);
        acc1 += fmaxf(base.y + o.y, 0.f);
      }});
  }
  *(float2*)&RS[(ob + row) * HD + h2] = make_float2(acc0, acc1);
}

// ---------------------------------------------------------------------------
// k_layer: aggr = RS@ew2 + 512*eb2; x' = MLP([x,aggr]); u/v(next) = x'@ew1n.
// 128 blocks x 8 rows; 10 weight tiles pipelined through LDS.
// ---------------------------------------------------------------------------
__global__ __launch_bounds__(512) void k_layer(
    const float* __restrict__ xin, const float* __restrict__ RSp,
    const float* __restrict__ ew2, const float* __restrict__ eb2,
    const float* __restrict__ nw1, const float* __restrict__ nb1,
    const float* __restrict__ nw2, const float* __restrict__ nb2,
    const float* __restrict__ ew1n, const float* __restrict__ eb1n,
    float* __restrict__ xout, float* __restrict__ u, float* __restrict__ v) {
  __shared__ float smem[13312];
  float* Wb = smem;
  float (*xa)[HD] = (float(*)[HD])(smem + 8192);
  float (*rs)[HD] = (float(*)[HD])(smem + 9216);
  float (*ag)[HD] = (float(*)[HD])(smem + 10240);
  float (*h1)[HD] = (float(*)[HD])(smem + 11264);
  float (*xo)[HD] = (float(*)[HD])(smem + 12288);
  const int tid = threadIdx.x;
  const int b = blockIdx.x;
  const bool isBird = b < 64;
  const int r0 = b * 8;
  const int c2 = (tid & 63) * 2;
  const int row = tid >> 6;
  if (tid < 256) ((f4*)xa)[tid]       = ((const f4*)(xin + r0 * HD))[tid];
  else           ((f4*)rs)[tid - 256] = ((const f4*)(RSp + r0 * HD))[tid - 256];
  f4 pf[4];
  TILE_GET(ew2);
  float2 be2 = *(const float2*)&eb2[c2];
  float2 bn1 = *(const float2*)&nb1[c2];
  float2 bn2 = *(const float2*)&nb2[c2];
  float2 be1 = isBird ? *(const float2*)&eb1n[c2] : make_float2(0.f, 0.f);
  const float* w1b = ew1n + (isBird ? 0 : 16384);

  float acc0 = 512.f * be2.x, acc1 = 512.f * be2.y;        // aggr
  ROUND(ew2 + 8192, MM64(&rs[0][0], HD, row, 0));
  ROUND(nw1,        MM64(&rs[0][0], HD, row, 64));
  ag[row][c2] = acc0; ag[row][c2 + 1] = acc1;
  acc0 = bn1.x; acc1 = bn1.y;                              // node layer 1
  ROUND(nw1 + 8192,  MM64(&xa[0][0], HD, row, 0));
  ROUND(nw1 + 16384, MM64(&xa[0][0], HD, row, 64));
  ROUND(nw1 + 24576, MM64(&ag[0][0], HD, row, 0));
  ROUND(nw2,         MM64(&ag[0][0], HD, row, 64));
  h1[row][c2] = fmaxf(acc0, 0.f); h1[row][c2 + 1] = fmaxf(acc1, 0.f);
  acc0 = bn2.x; acc1 = bn2.y;                              // node layer 2
  ROUND(nw2 + 8192, MM64(&h1[0][0], HD, row, 0));
  ROUND(w1b,        MM64(&h1[0][0], HD, row, 64));
  xo[row][c2] = acc0; xo[row][c2 + 1] = acc1;
  *(float2*)&xout[(r0 + row) * HD + c2] = make_float2(acc0, acc1);
  acc0 = be1.x; acc1 = be1.y;                              // next-layer u/v
  ROUND(w1b + 8192, MM64(&xo[0][0], HD, row, 0));
  ROUND(nullptr,    MM64(&xo[0][0], HD, row, 64));
  if (isBird) *(float2*)&u[(r0 + row) * HD + c2]      = make_float2(acc0, acc1);
  else        *(float2*)&v[(r0 - NB + row) * HD + c2] = make_float2(acc0, acc1);
}

// ---------------------------------------------------------------------------
// k_last: bird rows only. R (from u,v) + aggr + node MLP + gnn scores +
// mask/gather epilogue -> d_out. 128 blocks x 4 rows, 24 pipelined tiles.
// ---------------------------------------------------------------------------
__global__ __launch_bounds__(512) void k_last(
    const float* __restrict__ xin, const float* __restrict__ u,
    const float* __restrict__ v, const float* __restrict__ ew2,
    const float* __restrict__ eb2, const float* __restrict__ nw1,
    const float* __restrict__ nb1, const float* __restrict__ nw2,
    const float* __restrict__ nb2, const float* __restrict__ cpw,
    const float* __restrict__ cpb, const float* __restrict__ probs,
    const int* __restrict__ idx, float* __restrict__ out) {
  __shared__ float smem[12800];
  float* Wb = smem;                                   // 8192
  float (*xa)[HD] = (float(*)[HD])(smem + 8192);      // 4x128 each
  float (*Rl)[HD] = (float(*)[HD])(smem + 8704);
  float (*ag)[HD] = (float(*)[HD])(smem + 9216);
  float (*h1)[HD] = (float(*)[HD])(smem + 9728);
  float (*xo)[HD] = (float(*)[HD])(smem + 10240);
  float (*comb)[NC] = (float(*)[NC])(smem + 10752);   // 4x512
  const int tid = threadIdx.x;
  const int r0 = blockIdx.x * 4;
  const int h = tid & 127, rrow = tid >> 7;           // R-phase layout
  const int c2 = (tid & 63) * 2, slot = tid >> 6;     // matmul layout
  if (tid < 128) ((f4*)xa)[tid] = ((const f4*)(xin + r0 * HD))[tid];
  float pr[4];
  _Pragma("unroll") for (int r = 0; r < 4; ++r) pr[r] = probs[(r0 + r) * NC + tid];
  const float ubase = u[(r0 + rrow) * HD + h];
  f4 pf[4];
  TILE_GET(v);
  float racc = 0.f;                                   // R over 8 v-tiles
  for (int t = 0; t < 8; ++t) {
    const float* ns = (t < 7) ? (v + (t + 1) * 8192) : ew2;
    ROUND(ns, {
      _Pragma("unroll 16") for (int j = 0; j < 64; ++j)
        racc += fmaxf(ubase + Wb[j * HD + h], 0.f);
    });
  }
  Rl[rrow][h] = racc;
  float acc0 = 0.f, acc1 = 0.f;
  if (slot < 4) { float2 t_ = *(const float2*)&eb2[c2]; acc0 = 512.f * t_.x; acc1 = 512.f * t_.y; }
  ROUND(ew2 + 8192, if (slot < 4) MM64(&Rl[0][0], HD, slot, 0));
  ROUND(nw1,        if (slot < 4) MM64(&Rl[0][0], HD, slot, 64));
  if (slot < 4) { ag[slot][c2] = acc0; ag[slot][c2 + 1] = acc1;
                  float2 t_ = *(const float2*)&nb1[c2]; acc0 = t_.x; acc1 = t_.y; }
  ROUND(nw1 + 8192,  if (slot < 4) MM64(&xa[0][0], HD, slot, 0));
  ROUND(nw1 + 16384, if (slot < 4) MM64(&xa[0][0], HD, slot, 64));
  ROUND(nw1 + 24576, if (slot < 4) MM64(&ag[0][0], HD, slot, 0));
  ROUND(nw2,         if (slot < 4) MM64(&ag[0][0], HD, slot, 64));
  if (slot < 4) { h1[slot][c2] = fmaxf(acc0, 0.f); h1[slot][c2 + 1] = fmaxf(acc1, 0.f);
                  float2 t_ = *(const float2*)&nb2[c2]; acc0 = t_.x; acc1 = t_.y; }
  ROUND(nw2 + 8192, if (slot < 4) MM64(&h1[0][0], HD, slot, 0));
  ROUND(cpw,        if (slot < 4) MM64(&h1[0][0], HD, slot, 64));
  if (slot < 4) { xo[slot][c2] = acc0; xo[slot][c2 + 1] = acc1; }
  // gnn scores: 8 cpw tiles [16k][512]; thread owns one column, 4 rows
  float s0 = cpb[tid], s1 = s0, s2 = s0, s3 = s0;
  for (int t = 0; t < 8; ++t) {
    const float* ns = (t < 7) ? (cpw + (t + 1) * 8192) : (const float*)nullptr;
    ROUND(ns, {
      _Pragma("unroll") for (int k_ = 0; k_ < 16; ++k_) {
        float w_ = Wb[k_ * NC + tid];
        int kk = t * 16 + k_;
        s0 = fmaf(xo[0][kk], w_, s0);
        s1 = fmaf(xo[1][kk], w_, s1);
        s2 = fmaf(xo[2][kk], w_, s2);
        s3 = fmaf(xo[3][kk], w_, s3);
      }});
  }
  comb[0][tid] = s0 * pr[0]; comb[1][tid] = s1 * pr[1];
  comb[2][tid] = s2 * pr[2]; comb[3][tid] = s3 * pr[3];
  __syncthreads();
  _Pragma("unroll") for (int r = 0; r < 4; ++r) {
    int cc = idx[(r0 + r) * NC + tid];
    out[(r0 + r) * NC + tid] = 1.0f - comb[r][cc];
  }
}

extern "C" void kernel_launch(void* const* d_in, const int* in_sizes, int n_in,
                              void* d_out, int out_size, void* d_ws, size_t ws_size,
                              hipStream_t stream) {
  const float* probs = (const float*)d_in[0];
  const float* npw   = (const float*)d_in[1];
  const float* npb   = (const float*)d_in[2];
  const float* ew1   = (const float*)d_in[3];
  const float* eb1   = (const float*)d_in[4];
  const float* ew2   = (const float*)d_in[5];
  const float* eb2   = (const float*)d_in[6];
  const float* nw1   = (const float*)d_in[7];
  const float* nb1   = (const float*)d_in[8];
  const float* nw2   = (const float*)d_in[9];
  const float* nb2   = (const float*)d_in[10];
  const float* cpw   = (const float*)d_in[11];
  const float* cpb   = (const float*)d_in[12];
  float* out = (float*)d_out;

  float* x0 = (float*)d_ws;          // 1024*128
  float* x1 = x0 + 1024 * HD;        // 1024*128
  float* u  = x1 + 1024 * HD;        // 512*128
  float* v  = u + NB * HD;           // 512*128
  float* RS = v + NC * HD;           // 1024*128
  int*  idx = (int*)(RS + 1024 * HD);

  k_pre  <<<640, 512, 0, stream>>>(probs, npw, npb, ew1, eb1, x0, u, v, idx);
  k_RS   <<<128, 512, 0, stream>>>(u, v, RS);
  k_layer<<<128, 512, 0, stream>>>(x0, RS, ew2, eb2, nw1, nb1, nw2, nb2,
                                   ew1 + 32768, eb1 + HD, x1, u, v);
  k_RS   <<<128, 512, 0, stream>>>(u, v, RS);
  k_layer<<<128, 512, 0, stream>>>(x1, RS, ew2 + 16384, eb2 + HD,
                                   nw1 + 32768, nb1 + HD, nw2 + 16384, nb2 + HD,
                                   ew1 + 65536, eb1 + 2 * HD, x0, u, v);
  k_last <<<128, 512, 0, stream>>>(x0, u, v, ew2 + 32768, eb2 + 2 * HD,
                                   nw1 + 65536, nb1 + 2 * HD, nw2 + 32768, nb2 + 2 * HD,
                                   cpw, cpb, probs, idx, out);
}